// Round 4
// baseline (5727.116 us; speedup 1.0000x reference)
//
#include <hip/hip_runtime.h>

// ---------------------------------------------------------------------------
// BernNet forward: x@W1+b1 -> relu -> 2x BernConv(K=10) -> h@W2+b2
// h-domain math (per-edge f32 weight). CSR sorted by dst, packed 8B records
// (src, w). Fused Chebyshev step kernels; gather is 2 edges/wave-iteration
// x float4 x 4-deep unroll. NOTE: gather trip count MUST be wave-uniform --
// divergent halves make __shfl read inactive lanes (undefined on CDNA).
// Padding iterations shuffle from a lane holding (0, 0.0f) -> contribute 0.
// ---------------------------------------------------------------------------

#define SCAN_BLOCK 256
#define SCAN_ITEMS 4
#define SCAN_CHUNK 1024

__global__ __launch_bounds__(256) void hist_kernel(const int* __restrict__ src,
                                                   const int* __restrict__ dst,
                                                   int* __restrict__ deg_src,
                                                   int* __restrict__ cnt_dst, int E) {
    int stride = gridDim.x * blockDim.x;
    for (int e = blockIdx.x * blockDim.x + threadIdx.x; e < E; e += stride) {
        atomicAdd(&deg_src[src[e]], 1);
        atomicAdd(&cnt_dst[dst[e]], 1);
    }
}

__global__ __launch_bounds__(256) void dinv_kernel(const int* __restrict__ deg,
                                                   float* __restrict__ dinv, int n) {
    int i = blockIdx.x * blockDim.x + threadIdx.x;
    if (i < n) {
        int d = deg[i];
        dinv[i] = d > 0 ? rsqrtf((float)d) : 0.f;
    }
}

__global__ __launch_bounds__(SCAN_BLOCK) void scan_chunk_sum(const int* __restrict__ cnt,
                                                             int* __restrict__ bsum, int n) {
    __shared__ int sdata[SCAN_BLOCK];
    int tid = threadIdx.x;
    int base = blockIdx.x * SCAN_CHUNK + tid * SCAN_ITEMS;
    int s = 0;
    for (int i = 0; i < SCAN_ITEMS; ++i) {
        int idx = base + i;
        if (idx < n) s += cnt[idx];
    }
    sdata[tid] = s;
    __syncthreads();
    for (int off = SCAN_BLOCK / 2; off > 0; off >>= 1) {
        if (tid < off) sdata[tid] += sdata[tid + off];
        __syncthreads();
    }
    if (tid == 0) bsum[blockIdx.x] = sdata[0];
}

__global__ void scan_bsum(int* __restrict__ bsum, int nb) {
    if (threadIdx.x == 0 && blockIdx.x == 0) {
        int run = 0;
        for (int i = 0; i < nb; ++i) {
            int v = bsum[i];
            bsum[i] = run;
            run += v;
        }
    }
}

__global__ __launch_bounds__(SCAN_BLOCK) void scan_write(const int* __restrict__ cnt,
                                                         const int* __restrict__ bsum,
                                                         int* __restrict__ rowptr,
                                                         int* __restrict__ cursor,
                                                         int n, int total) {
    __shared__ int sdata[SCAN_BLOCK];
    int tid = threadIdx.x;
    int base = blockIdx.x * SCAN_CHUNK + tid * SCAN_ITEMS;
    int vals[SCAN_ITEMS];
    int s = 0;
    for (int i = 0; i < SCAN_ITEMS; ++i) {
        int idx = base + i;
        vals[i] = (idx < n) ? cnt[idx] : 0;
        s += vals[i];
    }
    sdata[tid] = s;
    __syncthreads();
    // Hillis-Steele inclusive scan
    for (int off = 1; off < SCAN_BLOCK; off <<= 1) {
        int add = (tid >= off) ? sdata[tid - off] : 0;
        __syncthreads();
        sdata[tid] += add;
        __syncthreads();
    }
    int run = bsum[blockIdx.x] + sdata[tid] - s;  // exclusive offset for this thread
    for (int i = 0; i < SCAN_ITEMS; ++i) {
        int idx = base + i;
        if (idx < n) {
            rowptr[idx] = run;
            cursor[idx] = run;
        }
        run += vals[i];
    }
    if (blockIdx.x == 0 && tid == 0) rowptr[n] = total;
}

// one packed 8B record per edge: (src index, f32 weight)
__global__ __launch_bounds__(256) void scatter_kernel(const int* __restrict__ src,
                                                      const int* __restrict__ dst,
                                                      const float* __restrict__ dinv,
                                                      int* __restrict__ cursor,
                                                      int2* __restrict__ colw, int E) {
    int stride = gridDim.x * blockDim.x;
    for (int e = blockIdx.x * blockDim.x + threadIdx.x; e < E; e += stride) {
        int s = src[e];
        int d = dst[e];
        float w = -0.5f * dinv[s] * dinv[d];
        int p = atomicAdd(&cursor[d], 1);
        int2 rec;
        rec.x = s;
        rec.y = __float_as_int(w);
        colw[p] = rec;
    }
}

// -------------------- GEMM1: h = relu(x @ W1 + b1), K=256, cols=128 --------
#define G1_ROWS 16
__global__ __launch_bounds__(128) void gemm1_kernel(const float* __restrict__ X,
                                                    const float* __restrict__ W,
                                                    const float* __restrict__ b,
                                                    float* __restrict__ H, int n) {
    __shared__ float xt[G1_ROWS][256];
    int j = threadIdx.x;  // output column 0..127
    int r0 = blockIdx.x * G1_ROWS;
    for (int i = threadIdx.x; i < G1_ROWS * 256; i += 128) {
        int r = i >> 8, k = i & 255;
        int row = r0 + r;
        xt[r][k] = (row < n) ? X[(size_t)row * 256 + k] : 0.f;
    }
    __syncthreads();
    float acc[G1_ROWS];
#pragma unroll
    for (int r = 0; r < G1_ROWS; ++r) acc[r] = 0.f;
    for (int k = 0; k < 256; ++k) {
        float wk = W[k * 128 + j];
#pragma unroll
        for (int r = 0; r < G1_ROWS; ++r) acc[r] += xt[r][k] * wk;
    }
    float bj = b[j];
    for (int r = 0; r < G1_ROWS; ++r) {
        int row = r0 + r;
        if (row < n) H[(size_t)row * 128 + j] = fmaxf(acc[r] + bj, 0.f);
    }
}

// -------------------- GEMM2: out = h @ W2 + b2, K=128, cols=64 -------------
#define G2_ROWS 32
__global__ __launch_bounds__(64) void gemm2_kernel(const float* __restrict__ H,
                                                   const float* __restrict__ W,
                                                   const float* __restrict__ b,
                                                   float* __restrict__ O, int n) {
    __shared__ float xt[G2_ROWS][128];
    int j = threadIdx.x;  // output column 0..63
    int r0 = blockIdx.x * G2_ROWS;
    for (int i = threadIdx.x; i < G2_ROWS * 128; i += 64) {
        int r = i >> 7, k = i & 127;
        int row = r0 + r;
        xt[r][k] = (row < n) ? H[(size_t)row * 128 + k] : 0.f;
    }
    __syncthreads();
    float acc[G2_ROWS];
#pragma unroll
    for (int r = 0; r < G2_ROWS; ++r) acc[r] = 0.f;
    for (int k = 0; k < 128; ++k) {
        float wk = W[k * 64 + j];
#pragma unroll
        for (int r = 0; r < G2_ROWS; ++r) acc[r] += xt[r][k] * wk;
    }
    float bj = b[j];
    for (int r = 0; r < G2_ROWS; ++r) {
        int row = r0 + r;
        if (row < n) O[(size_t)row * 64 + j] = acc[r] + bj;
    }
}

// -------------------- Fused Chebyshev propagation step ---------------------
// One wave per node. Two 32-lane halves each gather a different edge's source
// row as float4 (features 4q..4q+3), fma with the edge weight; 4 independent
// accumulators per half give up to 8 outstanding row loads per wave.
// iters is wave-uniform (ceil(m/2) for BOTH halves): half 1's padding
// iteration (odd m) shuffles from lane m, which holds (0, 0.0f) -> adds 0.
// acc = agg = sum_e w_e * X[col[e]]
// mode 0: tx1 = 0.5x - agg -> TX1; OUT = c0*x + c1*tx1
// mode 1: tx2 = x - 2*agg - t0; OUT += ck*tx2; T0 <- tx2
// mode 2: T0 <- relu(OUT + ck*tx2)   (layer end)
__global__ __launch_bounds__(256) void prop_kernel(const float* __restrict__ X,
                                                   float* __restrict__ T0,
                                                   float* __restrict__ OUT,
                                                   float* __restrict__ TX1,
                                                   const int* __restrict__ rowptr,
                                                   const int2* __restrict__ colw,
                                                   const float* __restrict__ coeffs,
                                                   int cidx, int mode, int n) {
    int wave = (blockIdx.x * blockDim.x + threadIdx.x) >> 6;
    if (wave >= n) return;
    int lane = threadIdx.x & 63;
    int half = lane >> 5;
    int q = lane & 31;
    int v = wave;
    int start = rowptr[v];
    int end = rowptr[v + 1];

    const float4* __restrict__ X4 = reinterpret_cast<const float4*>(X);
    float4 a0 = {0, 0, 0, 0}, a1 = {0, 0, 0, 0}, a2 = {0, 0, 0, 0}, a3 = {0, 0, 0, 0};

    for (int e0 = start; e0 < end; e0 += 64) {
        int m = end - e0;
        if (m > 64) m = 64;
        int sE = 0;
        float wE = 0.f;
        if (lane < m) {
            int2 rec = colw[e0 + lane];
            sE = rec.x;
            wE = __int_as_float(rec.y);
        }
        // WAVE-UNIFORM trip count: both halves run ceil(m/2) iterations.
        // For odd m, half 1's last shuffle reads lane m (holds sE=0, wE=0).
        int iters = (m + 1) >> 1;
        int t = 0;
        for (; t + 4 <= iters; t += 4) {
            int j0 = 2 * t + half;
            int s0 = __shfl(sE, j0);
            int s1 = __shfl(sE, j0 + 2);
            int s2 = __shfl(sE, j0 + 4);
            int s3 = __shfl(sE, j0 + 6);
            float w0 = __shfl(wE, j0);
            float w1 = __shfl(wE, j0 + 2);
            float w2 = __shfl(wE, j0 + 4);
            float w3 = __shfl(wE, j0 + 6);
            float4 x0 = X4[(size_t)s0 * 32 + q];
            float4 x1 = X4[(size_t)s1 * 32 + q];
            float4 x2 = X4[(size_t)s2 * 32 + q];
            float4 x3 = X4[(size_t)s3 * 32 + q];
            a0.x += w0 * x0.x; a0.y += w0 * x0.y; a0.z += w0 * x0.z; a0.w += w0 * x0.w;
            a1.x += w1 * x1.x; a1.y += w1 * x1.y; a1.z += w1 * x1.z; a1.w += w1 * x1.w;
            a2.x += w2 * x2.x; a2.y += w2 * x2.y; a2.z += w2 * x2.z; a2.w += w2 * x2.w;
            a3.x += w3 * x3.x; a3.y += w3 * x3.y; a3.z += w3 * x3.z; a3.w += w3 * x3.w;
        }
        for (; t < iters; ++t) {
            int j0 = 2 * t + half;
            int s0 = __shfl(sE, j0);
            float w0 = __shfl(wE, j0);
            float4 x0 = X4[(size_t)s0 * 32 + q];
            a0.x += w0 * x0.x; a0.y += w0 * x0.y; a0.z += w0 * x0.z; a0.w += w0 * x0.w;
        }
    }
    float4 acc;
    acc.x = (a0.x + a1.x) + (a2.x + a3.x);
    acc.y = (a0.y + a1.y) + (a2.y + a3.y);
    acc.z = (a0.z + a1.z) + (a2.z + a3.z);
    acc.w = (a0.w + a1.w) + (a2.w + a3.w);
    acc.x += __shfl_xor(acc.x, 32);
    acc.y += __shfl_xor(acc.y, 32);
    acc.z += __shfl_xor(acc.z, 32);
    acc.w += __shfl_xor(acc.w, 32);

    if (half) return;  // lanes 0..31 run the epilogue (32 x float4 = full row)

    size_t idx = (size_t)v * 32 + q;
    float4 self = X4[idx];

    if (mode == 0) {
        float c0 = coeffs[cidx];
        float c1 = coeffs[cidx + 1];
        float4 t1;
        t1.x = 0.5f * self.x - acc.x;
        t1.y = 0.5f * self.y - acc.y;
        t1.z = 0.5f * self.z - acc.z;
        t1.w = 0.5f * self.w - acc.w;
        reinterpret_cast<float4*>(TX1)[idx] = t1;
        float4 o;
        o.x = c0 * self.x + c1 * t1.x;
        o.y = c0 * self.y + c1 * t1.y;
        o.z = c0 * self.z + c1 * t1.z;
        o.w = c0 * self.w + c1 * t1.w;
        reinterpret_cast<float4*>(OUT)[idx] = o;
    } else {
        float ck = coeffs[cidx];
        float4 t0v = reinterpret_cast<const float4*>(T0)[idx];
        float4 t2;
        t2.x = self.x - 2.f * acc.x - t0v.x;
        t2.y = self.y - 2.f * acc.y - t0v.y;
        t2.z = self.z - 2.f * acc.z - t0v.z;
        t2.w = self.w - 2.f * acc.w - t0v.w;
        float4 o = reinterpret_cast<float4*>(OUT)[idx];
        o.x += ck * t2.x;
        o.y += ck * t2.y;
        o.z += ck * t2.z;
        o.w += ck * t2.w;
        if (mode == 1) {
            reinterpret_cast<float4*>(T0)[idx] = t2;
            reinterpret_cast<float4*>(OUT)[idx] = o;
        } else {
            float4 r;
            r.x = fmaxf(o.x, 0.f);
            r.y = fmaxf(o.y, 0.f);
            r.z = fmaxf(o.z, 0.f);
            r.w = fmaxf(o.w, 0.f);
            reinterpret_cast<float4*>(T0)[idx] = r;
        }
    }
}

// ---------------------------------------------------------------------------

extern "C" void kernel_launch(void* const* d_in, const int* in_sizes, int n_in,
                              void* d_out, int out_size, void* d_ws, size_t ws_size,
                              hipStream_t stream) {
    const float* x      = (const float*)d_in[0];
    const int*   ei     = (const int*)d_in[1];
    const float* W1     = (const float*)d_in[2];
    const float* b1     = (const float*)d_in[3];
    const float* coeffs = (const float*)d_in[4];
    const float* W2     = (const float*)d_in[5];
    const float* b2     = (const float*)d_in[6];
    float* out = (float*)d_out;

    const int n = in_sizes[0] / 256;
    const int E = in_sizes[1] / 2;
    const int* src = ei;
    const int* dst = ei + E;

    char* ws = (char*)d_ws;
    size_t off = 0;
    auto alloc = [&](size_t bytes) -> void* {
        off = (off + 255) & ~(size_t)255;
        void* p = (void*)(ws + off);
        off += bytes;
        return p;
    };
    size_t bufBytes = (size_t)n * 128 * sizeof(float);
    float* bufA   = (float*)alloc(bufBytes);
    float* bufB   = (float*)alloc(bufBytes);
    float* bufC   = (float*)alloc(bufBytes);
    int2*  colw   = (int2*)alloc((size_t)E * sizeof(int2));
    int*   degs   = (int*)alloc((size_t)n * sizeof(int));
    int*   cntd   = (int*)alloc((size_t)n * sizeof(int));
    int*   rowptr = (int*)alloc((size_t)(n + 1) * sizeof(int));
    int*   cursor = (int*)alloc((size_t)n * sizeof(int));
    int*   bsum   = (int*)alloc(1024 * sizeof(int));
    float* dinv   = (float*)alloc((size_t)n * sizeof(float));

    hipMemsetAsync(degs, 0, (size_t)n * sizeof(int), stream);
    hipMemsetAsync(cntd, 0, (size_t)n * sizeof(int), stream);

    // ---- CSR build (by dst) + packed edge weights ----
    hist_kernel<<<2048, 256, 0, stream>>>(src, dst, degs, cntd, E);
    dinv_kernel<<<(n + 255) / 256, 256, 0, stream>>>(degs, dinv, n);
    int nchunk = (n + SCAN_CHUNK - 1) / SCAN_CHUNK;
    scan_chunk_sum<<<nchunk, SCAN_BLOCK, 0, stream>>>(cntd, bsum, n);
    scan_bsum<<<1, 64, 0, stream>>>(bsum, nchunk);
    scan_write<<<nchunk, SCAN_BLOCK, 0, stream>>>(cntd, bsum, rowptr, cursor, n, E);
    scatter_kernel<<<4096, 256, 0, stream>>>(src, dst, dinv, cursor, colw, E);

    // ---- h = relu(x @ W1 + b1) ----
    gemm1_kernel<<<(n + G1_ROWS - 1) / G1_ROWS, 128, 0, stream>>>(x, W1, b1, bufA, n);

    // ---- 2 BernConv layers ----
    int pgrid = (n + 3) / 4;  // 4 waves (nodes) per 256-thread block
    float* A = bufA;
    float* B = bufB;
    float* C = bufC;
    for (int l = 0; l < 2; ++l) {
        // k=0,1 fused: tx1 = 0.5x - agg(x); out = c0*x + c1*tx1
        prop_kernel<<<pgrid, 256, 0, stream>>>(A, A, C, B, rowptr, colw, coeffs,
                                               l * 11 + 0, 0, n);
        float* t0 = A;
        float* t1 = B;
        for (int k = 2; k <= 9; ++k) {
            prop_kernel<<<pgrid, 256, 0, stream>>>(t1, t0, C, nullptr, rowptr, colw,
                                                   coeffs, l * 11 + k, 1, n);
            float* tmp = t0; t0 = t1; t1 = tmp;  // tx0 <- tx1, tx1 <- tx2
        }
        // k=10: fold last term + ReLU; layer output lands in t0's buffer
        prop_kernel<<<pgrid, 256, 0, stream>>>(t1, t0, C, nullptr, rowptr, colw,
                                               coeffs, l * 11 + 10, 2, n);
        A = t0;  // next layer input
        B = t1;  // free buffer
    }

    // ---- out = h @ W2 + b2 ----
    gemm2_kernel<<<(n + G2_ROWS - 1) / G2_ROWS, 64, 0, stream>>>(A, W2, b2, out, n);
}

// Round 5
// 3461.776 us; speedup vs baseline: 1.6544x; 1.6544x over previous
//
#include <hip/hip_runtime.h>
#include <hip/hip_fp16.h>

// ---------------------------------------------------------------------------
// BernNet forward: x@W1+b1 -> relu -> 2x BernConv(K=10) -> h@W2+b2
// h-domain math, f32 recurrence state. The edge GATHER reads an fp16 mirror
// (256B rows) of the current T-vector: halves beyond-L2 gather bytes and the
// working set. CSR by dst, packed 8B (src,w) records. Gather trip count is
// wave-uniform (divergent __shfl is undefined on CDNA; padding lane holds 0).
// ---------------------------------------------------------------------------

#define SCAN_BLOCK 256
#define SCAN_ITEMS 4
#define SCAN_CHUNK 1024

union h2cvt {
    float2 f2;
    __half2 h2[2];
};

__global__ __launch_bounds__(256) void hist_kernel(const int* __restrict__ src,
                                                   const int* __restrict__ dst,
                                                   int* __restrict__ deg_src,
                                                   int* __restrict__ cnt_dst, int E) {
    int stride = gridDim.x * blockDim.x;
    for (int e = blockIdx.x * blockDim.x + threadIdx.x; e < E; e += stride) {
        atomicAdd(&deg_src[src[e]], 1);
        atomicAdd(&cnt_dst[dst[e]], 1);
    }
}

__global__ __launch_bounds__(256) void dinv_kernel(const int* __restrict__ deg,
                                                   float* __restrict__ dinv, int n) {
    int i = blockIdx.x * blockDim.x + threadIdx.x;
    if (i < n) {
        int d = deg[i];
        dinv[i] = d > 0 ? rsqrtf((float)d) : 0.f;
    }
}

__global__ __launch_bounds__(SCAN_BLOCK) void scan_chunk_sum(const int* __restrict__ cnt,
                                                             int* __restrict__ bsum, int n) {
    __shared__ int sdata[SCAN_BLOCK];
    int tid = threadIdx.x;
    int base = blockIdx.x * SCAN_CHUNK + tid * SCAN_ITEMS;
    int s = 0;
    for (int i = 0; i < SCAN_ITEMS; ++i) {
        int idx = base + i;
        if (idx < n) s += cnt[idx];
    }
    sdata[tid] = s;
    __syncthreads();
    for (int off = SCAN_BLOCK / 2; off > 0; off >>= 1) {
        if (tid < off) sdata[tid] += sdata[tid + off];
        __syncthreads();
    }
    if (tid == 0) bsum[blockIdx.x] = sdata[0];
}

__global__ void scan_bsum(int* __restrict__ bsum, int nb) {
    if (threadIdx.x == 0 && blockIdx.x == 0) {
        int run = 0;
        for (int i = 0; i < nb; ++i) {
            int v = bsum[i];
            bsum[i] = run;
            run += v;
        }
    }
}

__global__ __launch_bounds__(SCAN_BLOCK) void scan_write(const int* __restrict__ cnt,
                                                         const int* __restrict__ bsum,
                                                         int* __restrict__ rowptr,
                                                         int* __restrict__ cursor,
                                                         int n, int total) {
    __shared__ int sdata[SCAN_BLOCK];
    int tid = threadIdx.x;
    int base = blockIdx.x * SCAN_CHUNK + tid * SCAN_ITEMS;
    int vals[SCAN_ITEMS];
    int s = 0;
    for (int i = 0; i < SCAN_ITEMS; ++i) {
        int idx = base + i;
        vals[i] = (idx < n) ? cnt[idx] : 0;
        s += vals[i];
    }
    sdata[tid] = s;
    __syncthreads();
    for (int off = 1; off < SCAN_BLOCK; off <<= 1) {
        int add = (tid >= off) ? sdata[tid - off] : 0;
        __syncthreads();
        sdata[tid] += add;
        __syncthreads();
    }
    int run = bsum[blockIdx.x] + sdata[tid] - s;
    for (int i = 0; i < SCAN_ITEMS; ++i) {
        int idx = base + i;
        if (idx < n) {
            rowptr[idx] = run;
            cursor[idx] = run;
        }
        run += vals[i];
    }
    if (blockIdx.x == 0 && tid == 0) rowptr[n] = total;
}

// one packed 8B record per edge: (src index, f32 weight)
__global__ __launch_bounds__(256) void scatter_kernel(const int* __restrict__ src,
                                                      const int* __restrict__ dst,
                                                      const float* __restrict__ dinv,
                                                      int* __restrict__ cursor,
                                                      int2* __restrict__ colw, int E) {
    int stride = gridDim.x * blockDim.x;
    for (int e = blockIdx.x * blockDim.x + threadIdx.x; e < E; e += stride) {
        int s = src[e];
        int d = dst[e];
        float w = -0.5f * dinv[s] * dinv[d];
        int p = atomicAdd(&cursor[d], 1);
        int2 rec;
        rec.x = s;
        rec.y = __float_as_int(w);
        colw[p] = rec;
    }
}

// f32 -> fp16 mirror (float4 -> 4 halves packed in a float2)
__global__ __launch_bounds__(256) void tofp16_kernel(const float4* __restrict__ in,
                                                     float2* __restrict__ outh, int n4) {
    int stride = gridDim.x * blockDim.x;
    for (int i = blockIdx.x * blockDim.x + threadIdx.x; i < n4; i += stride) {
        float4 v = in[i];
        h2cvt c;
        c.h2[0] = __floats2half2_rn(v.x, v.y);
        c.h2[1] = __floats2half2_rn(v.z, v.w);
        outh[i] = c.f2;
    }
}

// -------------------- GEMM1: h = relu(x @ W1 + b1), K=256, cols=128 --------
#define G1_ROWS 16
__global__ __launch_bounds__(128) void gemm1_kernel(const float* __restrict__ X,
                                                    const float* __restrict__ W,
                                                    const float* __restrict__ b,
                                                    float* __restrict__ H, int n) {
    __shared__ float xt[G1_ROWS][256];
    int j = threadIdx.x;
    int r0 = blockIdx.x * G1_ROWS;
    for (int i = threadIdx.x; i < G1_ROWS * 256; i += 128) {
        int r = i >> 8, k = i & 255;
        int row = r0 + r;
        xt[r][k] = (row < n) ? X[(size_t)row * 256 + k] : 0.f;
    }
    __syncthreads();
    float acc[G1_ROWS];
#pragma unroll
    for (int r = 0; r < G1_ROWS; ++r) acc[r] = 0.f;
    for (int k = 0; k < 256; ++k) {
        float wk = W[k * 128 + j];
#pragma unroll
        for (int r = 0; r < G1_ROWS; ++r) acc[r] += xt[r][k] * wk;
    }
    float bj = b[j];
    for (int r = 0; r < G1_ROWS; ++r) {
        int row = r0 + r;
        if (row < n) H[(size_t)row * 128 + j] = fmaxf(acc[r] + bj, 0.f);
    }
}

// -------------------- GEMM2: out = h @ W2 + b2, K=128, cols=64 -------------
#define G2_ROWS 32
__global__ __launch_bounds__(64) void gemm2_kernel(const float* __restrict__ H,
                                                   const float* __restrict__ W,
                                                   const float* __restrict__ b,
                                                   float* __restrict__ O, int n) {
    __shared__ float xt[G2_ROWS][128];
    int j = threadIdx.x;
    int r0 = blockIdx.x * G2_ROWS;
    for (int i = threadIdx.x; i < G2_ROWS * 128; i += 64) {
        int r = i >> 7, k = i & 127;
        int row = r0 + r;
        xt[r][k] = (row < n) ? H[(size_t)row * 128 + k] : 0.f;
    }
    __syncthreads();
    float acc[G2_ROWS];
#pragma unroll
    for (int r = 0; r < G2_ROWS; ++r) acc[r] = 0.f;
    for (int k = 0; k < 128; ++k) {
        float wk = W[k * 64 + j];
#pragma unroll
        for (int r = 0; r < G2_ROWS; ++r) acc[r] += xt[r][k] * wk;
    }
    float bj = b[j];
    for (int r = 0; r < G2_ROWS; ++r) {
        int row = r0 + r;
        if (row < n) O[(size_t)row * 64 + j] = acc[r] + bj;
    }
}

// -------------------- Fused Chebyshev propagation step ---------------------
// One wave per node. Gather reads the fp16 MIRROR (XH, 256B rows); self/T0/
// OUT read the f32 masters. Two 32-lane halves, 2 edges/iter, 4-deep unroll.
// Trip count is wave-uniform; odd-m padding shuffles lane m (holds 0,0.0f).
// MH (may be null) receives the fp16 mirror of the value written this step.
// mode 0: tx1 = 0.5x - agg -> TX1 (+MH); OUT = c0*x + c1*tx1
// mode 1: tx2 = x - 2*agg - t0; OUT += ck*tx2; T0 <- tx2 (+MH)
// mode 2: T0 <- relu(OUT + ck*tx2) (+MH)   (layer end)
__global__ __launch_bounds__(256) void prop_kernel(const float* __restrict__ XF,
                                                   const float2* __restrict__ XH,
                                                   float* __restrict__ T0,
                                                   float* __restrict__ OUT,
                                                   float* __restrict__ TX1,
                                                   float2* __restrict__ MH,
                                                   const int* __restrict__ rowptr,
                                                   const int2* __restrict__ colw,
                                                   const float* __restrict__ coeffs,
                                                   int cidx, int mode, int n) {
    int wave = (blockIdx.x * blockDim.x + threadIdx.x) >> 6;
    if (wave >= n) return;
    int lane = threadIdx.x & 63;
    int half = lane >> 5;
    int q = lane & 31;
    int v = wave;
    int start = rowptr[v];
    int end = rowptr[v + 1];

    float4 a0 = {0, 0, 0, 0}, a1 = {0, 0, 0, 0}, a2 = {0, 0, 0, 0}, a3 = {0, 0, 0, 0};

    for (int e0 = start; e0 < end; e0 += 64) {
        int m = end - e0;
        if (m > 64) m = 64;
        int sE = 0;
        float wE = 0.f;
        if (lane < m) {
            int2 rec = colw[e0 + lane];
            sE = rec.x;
            wE = __int_as_float(rec.y);
        }
        // wave-uniform trip count (both halves): ceil(m/2)
        int iters = (m + 1) >> 1;
        int t = 0;
        for (; t + 4 <= iters; t += 4) {
            int j0 = 2 * t + half;
            int s0 = __shfl(sE, j0);
            int s1 = __shfl(sE, j0 + 2);
            int s2 = __shfl(sE, j0 + 4);
            int s3 = __shfl(sE, j0 + 6);
            float w0 = __shfl(wE, j0);
            float w1 = __shfl(wE, j0 + 2);
            float w2 = __shfl(wE, j0 + 4);
            float w3 = __shfl(wE, j0 + 6);
            h2cvt c0, c1, c2, c3;
            c0.f2 = XH[(size_t)s0 * 32 + q];
            c1.f2 = XH[(size_t)s1 * 32 + q];
            c2.f2 = XH[(size_t)s2 * 32 + q];
            c3.f2 = XH[(size_t)s3 * 32 + q];
            float2 lo, hi;
            lo = __half22float2(c0.h2[0]); hi = __half22float2(c0.h2[1]);
            a0.x += w0 * lo.x; a0.y += w0 * lo.y; a0.z += w0 * hi.x; a0.w += w0 * hi.y;
            lo = __half22float2(c1.h2[0]); hi = __half22float2(c1.h2[1]);
            a1.x += w1 * lo.x; a1.y += w1 * lo.y; a1.z += w1 * hi.x; a1.w += w1 * hi.y;
            lo = __half22float2(c2.h2[0]); hi = __half22float2(c2.h2[1]);
            a2.x += w2 * lo.x; a2.y += w2 * lo.y; a2.z += w2 * hi.x; a2.w += w2 * hi.y;
            lo = __half22float2(c3.h2[0]); hi = __half22float2(c3.h2[1]);
            a3.x += w3 * lo.x; a3.y += w3 * lo.y; a3.z += w3 * hi.x; a3.w += w3 * hi.y;
        }
        for (; t < iters; ++t) {
            int j0 = 2 * t + half;
            int s0 = __shfl(sE, j0);
            float w0 = __shfl(wE, j0);
            h2cvt c0;
            c0.f2 = XH[(size_t)s0 * 32 + q];
            float2 lo = __half22float2(c0.h2[0]);
            float2 hi = __half22float2(c0.h2[1]);
            a0.x += w0 * lo.x; a0.y += w0 * lo.y; a0.z += w0 * hi.x; a0.w += w0 * hi.y;
        }
    }
    float4 acc;
    acc.x = (a0.x + a1.x) + (a2.x + a3.x);
    acc.y = (a0.y + a1.y) + (a2.y + a3.y);
    acc.z = (a0.z + a1.z) + (a2.z + a3.z);
    acc.w = (a0.w + a1.w) + (a2.w + a3.w);
    acc.x += __shfl_xor(acc.x, 32);
    acc.y += __shfl_xor(acc.y, 32);
    acc.z += __shfl_xor(acc.z, 32);
    acc.w += __shfl_xor(acc.w, 32);

    if (half) return;  // lanes 0..31 run the epilogue

    size_t idx = (size_t)v * 32 + q;
    const float4* __restrict__ X4 = reinterpret_cast<const float4*>(XF);
    float4 self = X4[idx];
    float4 wr;  // value written to the T-buffer this step (mirrored to MH)

    if (mode == 0) {
        float c0 = coeffs[cidx];
        float c1 = coeffs[cidx + 1];
        wr.x = 0.5f * self.x - acc.x;
        wr.y = 0.5f * self.y - acc.y;
        wr.z = 0.5f * self.z - acc.z;
        wr.w = 0.5f * self.w - acc.w;
        reinterpret_cast<float4*>(TX1)[idx] = wr;
        float4 o;
        o.x = c0 * self.x + c1 * wr.x;
        o.y = c0 * self.y + c1 * wr.y;
        o.z = c0 * self.z + c1 * wr.z;
        o.w = c0 * self.w + c1 * wr.w;
        reinterpret_cast<float4*>(OUT)[idx] = o;
    } else {
        float ck = coeffs[cidx];
        float4 t0v = reinterpret_cast<const float4*>(T0)[idx];
        float4 t2;
        t2.x = self.x - 2.f * acc.x - t0v.x;
        t2.y = self.y - 2.f * acc.y - t0v.y;
        t2.z = self.z - 2.f * acc.z - t0v.z;
        t2.w = self.w - 2.f * acc.w - t0v.w;
        float4 o = reinterpret_cast<float4*>(OUT)[idx];
        o.x += ck * t2.x;
        o.y += ck * t2.y;
        o.z += ck * t2.z;
        o.w += ck * t2.w;
        if (mode == 1) {
            wr = t2;
            reinterpret_cast<float4*>(T0)[idx] = wr;
            reinterpret_cast<float4*>(OUT)[idx] = o;
        } else {
            wr.x = fmaxf(o.x, 0.f);
            wr.y = fmaxf(o.y, 0.f);
            wr.z = fmaxf(o.z, 0.f);
            wr.w = fmaxf(o.w, 0.f);
            reinterpret_cast<float4*>(T0)[idx] = wr;
        }
    }
    if (MH) {
        h2cvt c;
        c.h2[0] = __floats2half2_rn(wr.x, wr.y);
        c.h2[1] = __floats2half2_rn(wr.z, wr.w);
        MH[idx] = c.f2;
    }
}

// ---------------------------------------------------------------------------

extern "C" void kernel_launch(void* const* d_in, const int* in_sizes, int n_in,
                              void* d_out, int out_size, void* d_ws, size_t ws_size,
                              hipStream_t stream) {
    const float* x      = (const float*)d_in[0];
    const int*   ei     = (const int*)d_in[1];
    const float* W1     = (const float*)d_in[2];
    const float* b1     = (const float*)d_in[3];
    const float* coeffs = (const float*)d_in[4];
    const float* W2     = (const float*)d_in[5];
    const float* b2     = (const float*)d_in[6];
    float* out = (float*)d_out;

    const int n = in_sizes[0] / 256;
    const int E = in_sizes[1] / 2;
    const int* src = ei;
    const int* dst = ei + E;

    char* ws = (char*)d_ws;
    size_t off = 0;
    auto alloc = [&](size_t bytes) -> void* {
        off = (off + 255) & ~(size_t)255;
        void* p = (void*)(ws + off);
        off += bytes;
        return p;
    };
    size_t bufBytes = (size_t)n * 128 * sizeof(float);
    size_t mirBytes = (size_t)n * 128 * sizeof(__half);
    float*  bufA   = (float*)alloc(bufBytes);
    float*  bufB   = (float*)alloc(bufBytes);
    float*  bufC   = (float*)alloc(bufBytes);
    float2* mirA   = (float2*)alloc(mirBytes);
    float2* mirB   = (float2*)alloc(mirBytes);
    int2*   colw   = (int2*)alloc((size_t)E * sizeof(int2));
    int*    degs   = (int*)alloc((size_t)n * sizeof(int));
    int*    cntd   = (int*)alloc((size_t)n * sizeof(int));
    int*    rowptr = (int*)alloc((size_t)(n + 1) * sizeof(int));
    int*    cursor = (int*)alloc((size_t)n * sizeof(int));
    int*    bsum   = (int*)alloc(1024 * sizeof(int));
    float*  dinv   = (float*)alloc((size_t)n * sizeof(float));

    hipMemsetAsync(degs, 0, (size_t)n * sizeof(int), stream);
    hipMemsetAsync(cntd, 0, (size_t)n * sizeof(int), stream);

    // ---- CSR build (by dst) + packed edge weights ----
    hist_kernel<<<2048, 256, 0, stream>>>(src, dst, degs, cntd, E);
    dinv_kernel<<<(n + 255) / 256, 256, 0, stream>>>(degs, dinv, n);
    int nchunk = (n + SCAN_CHUNK - 1) / SCAN_CHUNK;
    scan_chunk_sum<<<nchunk, SCAN_BLOCK, 0, stream>>>(cntd, bsum, n);
    scan_bsum<<<1, 64, 0, stream>>>(bsum, nchunk);
    scan_write<<<nchunk, SCAN_BLOCK, 0, stream>>>(cntd, bsum, rowptr, cursor, n, E);
    scatter_kernel<<<4096, 256, 0, stream>>>(src, dst, dinv, cursor, colw, E);

    // ---- h = relu(x @ W1 + b1) + fp16 mirror ----
    gemm1_kernel<<<(n + G1_ROWS - 1) / G1_ROWS, 128, 0, stream>>>(x, W1, b1, bufA, n);
    tofp16_kernel<<<2048, 256, 0, stream>>>((const float4*)bufA, mirA, n * 32);

    // ---- 2 BernConv layers ----
    int pgrid = (n + 3) / 4;  // 4 waves (nodes) per 256-thread block
    float*  A  = bufA;
    float*  B  = bufB;
    float*  C  = bufC;
    float2* mA = mirA;
    float2* mB = mirB;
    for (int l = 0; l < 2; ++l) {
        // k=0,1 fused: tx1 = 0.5x - agg(x) -> B (+mirror mB); out = c0*x + c1*tx1
        prop_kernel<<<pgrid, 256, 0, stream>>>(A, mA, A, C, B, mB, rowptr, colw,
                                               coeffs, l * 11 + 0, 0, n);
        float*  t0 = A;  float2* m0 = mA;
        float*  t1 = B;  float2* m1 = mB;
        for (int k = 2; k <= 9; ++k) {
            // gather from t1 (mirror m1); tx2 overwrites t0 (mirror m0)
            prop_kernel<<<pgrid, 256, 0, stream>>>(t1, m1, t0, C, nullptr, m0, rowptr,
                                                   colw, coeffs, l * 11 + k, 1, n);
            float* tf = t0; t0 = t1; t1 = tf;
            float2* tm = m0; m0 = m1; m1 = tm;
        }
        // k=10: fold last term + ReLU -> t0 (+mirror m0 if another layer follows)
        prop_kernel<<<pgrid, 256, 0, stream>>>(t1, m1, t0, C, nullptr,
                                               (l == 0) ? m0 : nullptr, rowptr,
                                               colw, coeffs, l * 11 + 10, 2, n);
        A = t0; mA = m0;   // next layer input (f32 + mirror)
        B = t1; mB = m1;
    }

    // ---- out = h @ W2 + b2 ----
    gemm2_kernel<<<(n + G2_ROWS - 1) / G2_ROWS, 64, 0, stream>>>(A, W2, b2, out, n);
}